// Round 8
// baseline (127.804 us; speedup 1.0000x reference)
//
#include <hip/hip_runtime.h>
#include <stdint.h>

#define NB     16
#define NANCH  65536
#define NC     21
#define NCLS   20
#define NCOL   (NB * NCLS)     // 320
#define TOPK   200
#define NBINS  1024
#define CAP    256
#define CAPCOL 4096
#define CNTSTRIDE 16           // one counter per 64B cache line
#define NPAIRS 19900           // TOPK*(TOPK-1)/2

constexpr float TH      = 0.05f;
constexpr float TPRE    = 0.15f;                  // pre-filter threshold
constexpr float SCALE15 = (float)NBINS / 0.85f;   // bins over [0.15, 1.0]
constexpr float SCALE05 = (float)NBINS / 0.95f;   // fallback bins [0.05, 1.0]

// ---- ws layout (bytes) ----
#define OFF_CAND  0LL          // 320*4096*8 = 10,485,760
#define OFF_CNT   10485760LL   // 320*16*4   = 20,480
#define OFF_SOA   10506240LL   // 6 arrays * 320*200*4 = 1,536,000
#define SOA_N     64000        // 320*200 floats per array
#define OFF_NSEL  12042240LL   // 320*16*4 = 20,480
#define OFF_ADJ   12062720LL   // 320*200*4*8 = 2,048,000

__device__ __forceinline__ int bin15(float s) {
  int b = (int)((s - 0.15f) * SCALE15);
  return b < 0 ? 0 : (b > NBINS - 1 ? NBINS - 1 : b);
}
__device__ __forceinline__ int bin05(float s) {
  int b = (int)((s - 0.05f) * SCALE05);
  return b < 0 ? 0 : (b > NBINS - 1 ? NBINS - 1 : b);
}

__device__ __forceinline__ unsigned long long shflx64(unsigned long long v, int m) {
  unsigned int lo = (unsigned int)v, hi = (unsigned int)(v >> 32);
  lo = __shfl_xor(lo, m);
  hi = __shfl_xor(hi, m);
  return ((unsigned long long)hi << 32) | lo;
}
__device__ __forceinline__ unsigned long long rl64(unsigned long long v, int lane) {
  unsigned int lo = __builtin_amdgcn_readlane((int)(unsigned int)v, lane);
  unsigned int hi = __builtin_amdgcn_readlane((int)(unsigned int)(v >> 32), lane);
  return ((unsigned long long)hi << 32) | lo;
}

// exact softmax tail (numpy pairwise sum for n=21)
__device__ __forceinline__ void softmax_tail(const float* x, float* e, float& S) {
  float m = x[0];
#pragma unroll
  for (int c = 1; c < NC; ++c) m = fmaxf(m, x[c]);
#pragma unroll
  for (int c = 0; c < NC; ++c) e[c] = expf(x[c] - m);
  float r0 = e[0] + e[8],  r1 = e[1] + e[9],  r2 = e[2] + e[10], r3 = e[3] + e[11];
  float r4 = e[4] + e[12], r5 = e[5] + e[13], r6 = e[6] + e[14], r7 = e[7] + e[15];
  S = ((r0 + r1) + (r2 + r3)) + ((r4 + r5) + (r6 + r7));
  S += e[16]; S += e[17]; S += e[18]; S += e[19]; S += e[20];
}

// ---------------- K1: softmax + candidate collection (unchanged) ------------
__global__ __launch_bounds__(256) void softmax_collect_kernel(
    const float* __restrict__ conf,
    unsigned int* __restrict__ cnt, unsigned long long* __restrict__ cand) {
  const int tid = threadIdx.x;
  __shared__ float ld[256 * NC];          // rows at odd stride 21
  const float4* src = (const float4*)conf + (long long)blockIdx.x * 1344;
  float4* dst4 = (float4*)ld;
#pragma unroll
  for (int i = 0; i < 5; ++i) dst4[tid + i * 256] = src[tid + i * 256];
  if (tid < 64) dst4[tid + 1280] = src[tid + 1280];
  __syncthreads();

  const int a = blockIdx.x * 256 + tid;
  const int b = a >> 16;
  const int n = a & (NANCH - 1);
  float x[NC];
#pragma unroll
  for (int c = 0; c < NC; ++c) x[c] = ld[tid * NC + c];
  float e[NC], S;
  softmax_tail(x, e, S);
  const float t = TPRE * S;               // div-free take test
  unsigned int takemask = 0;
#pragma unroll
  for (int c = 0; c < NCLS; ++c)
    if (e[c + 1] >= t) takemask |= (1u << c);

  __shared__ unsigned int wcnt[4][NCLS];
  __shared__ unsigned int wbase[4][NCLS];
  const int wave = tid >> 6, lane = tid & 63;
#pragma unroll
  for (int c = 0; c < NCLS; ++c) {
    unsigned long long m = __ballot((takemask >> c) & 1);
    if (lane == 0) wcnt[wave][c] = (unsigned int)__popcll(m);
  }
  __syncthreads();
  if (tid < NCLS) {
    const int c = tid;
    unsigned int t0 = wcnt[0][c], t1 = wcnt[1][c], t2 = wcnt[2][c], t3 = wcnt[3][c];
    unsigned int tot = t0 + t1 + t2 + t3;
    unsigned int base = tot ? atomicAdd(&cnt[(b * NCLS + c) * CNTSTRIDE], tot) : 0u;
    wbase[0][c] = base;
    wbase[1][c] = base + t0;
    wbase[2][c] = base + t0 + t1;
    wbase[3][c] = base + t0 + t1 + t2;
  }
  __syncthreads();
#pragma unroll
  for (int c = 0; c < NCLS; ++c) {
    bool take = (takemask >> c) & 1;
    unsigned long long m = __ballot(take);
    if (take) {
      float s = e[c + 1] / S;             // IEEE div, like np — takers only
      unsigned int off = wbase[wave][c] +
                         (unsigned int)__popcll(m & ((1ULL << lane) - 1));
      if (off < CAPCOL) {
        unsigned int key = __float_as_uint(s) | 0x80000000u;  // s > 0
        cand[(long long)(b * NCLS + c) * CAPCOL + off] =
            ((unsigned long long)(key ^ 0xFFFFFFFFu) << 32) |
            (unsigned long long)(unsigned int)n;
      }
    }
  }
}

// ---------------- wave-0 parallel cut-bin finder (1024 bins in LDS) ---------
__device__ __forceinline__ int find_sel(unsigned int* hist, unsigned int* part,
                                        int* s_sel, int tid) {
  unsigned int p = hist[tid*4] + hist[tid*4+1] + hist[tid*4+2] + hist[tid*4+3];
  part[tid] = p;
  if (tid == 0) *s_sel = -1;
  __syncthreads();
  if (tid < 64) {
    unsigned int p4 = part[tid*4] + part[tid*4+1] + part[tid*4+2] + part[tid*4+3];
    unsigned int sfx = p4;                 // inclusive suffix over 64 groups
#pragma unroll
    for (int off = 1; off < 64; off <<= 1) {
      unsigned int o = __shfl_down(sfx, off);
      if (tid + off < 64) sfx += o;
    }
    unsigned int above = sfx - p4;
    if (above < TOPK && sfx >= TOPK) {     // exactly one owner (if total>=200)
      unsigned int cum = above; int sel = tid * 16; bool found = false;
      for (int q = 3; q >= 0 && !found; --q) {
        unsigned int pc = part[tid*4 + q];
        if (cum + pc >= TOPK) {
          for (int i = 3; i >= 0; --i) {
            unsigned int c = hist[(tid*4+q)*4 + i];
            if (cum + c >= TOPK) { sel = (tid*4+q)*4 + i; found = true; break; }
            cum += c;
          }
        } else cum += pc;
      }
      *s_sel = sel;
    }
  }
  __syncthreads();
  return *s_sel;
}

// ---------------- K2: per-column select + sort + decode -> SoA --------------
__global__ __launch_bounds__(256) void select_sort_decode_kernel(
    const unsigned long long* __restrict__ candg,
    const unsigned int* __restrict__ cnt,
    const float* __restrict__ conf, const float* __restrict__ loc,
    const float* __restrict__ anchors, float* __restrict__ soa,
    int* __restrict__ nselg) {
  const int bc = blockIdx.x;
  const int b  = bc / NCLS;
  const int cls = bc % NCLS;
  const int tid = threadIdx.x;

  __shared__ unsigned long long cg_lds[CAPCOL];   // 32 KB
  __shared__ unsigned int hist[NBINS];
  __shared__ unsigned int part[256];
  __shared__ int s_sel, s_n;
  __shared__ unsigned long long cand[CAP];

  int nc = (int)cnt[bc * CNTSTRIDE];
  const bool fast = (nc >= TOPK && nc <= CAPCOL);
  for (int i = tid; i < NBINS; i += 256) hist[i] = 0;
  if (tid == 0) s_n = 0;
  __syncthreads();

  const unsigned long long* cg = candg + (long long)bc * CAPCOL;
  if (fast) {
    for (int i = tid; i < nc; i += 256) {         // single global pass
      unsigned long long k64 = cg[i];
      cg_lds[i] = k64;
      unsigned int key = (unsigned int)(k64 >> 32) ^ 0xFFFFFFFFu;
      float s = __uint_as_float(key ^ 0x80000000u);
      atomicAdd(&hist[bin15(s)], 1u);
    }
    __syncthreads();
    int sel = find_sel(hist, part, &s_sel, tid);
    for (int i = tid; i < nc; i += 256) {
      unsigned long long k64 = cg_lds[i];
      unsigned int key = (unsigned int)(k64 >> 32) ^ 0xFFFFFFFFu;
      float s = __uint_as_float(key ^ 0x80000000u);
      if (bin15(s) >= sel) {
        int pos = atomicAdd(&s_n, 1);
        if (pos < CAP) cand[pos] = k64;
      }
    }
  } else {
    for (int n = tid; n < NANCH; n += 256) {
      const float* row = conf + ((long long)b * NANCH + n) * NC;
      float x[NC], e[NC], S;
#pragma unroll
      for (int c = 0; c < NC; ++c) x[c] = row[c];
      softmax_tail(x, e, S);
      float s = e[cls + 1] / S;
      if (s >= TH) atomicAdd(&hist[bin05(s)], 1u);
    }
    __syncthreads();
    int sel = find_sel(hist, part, &s_sel, tid);
    for (int n = tid; n < NANCH; n += 256) {
      const float* row = conf + ((long long)b * NANCH + n) * NC;
      float x[NC], e[NC], S;
#pragma unroll
      for (int c = 0; c < NC; ++c) x[c] = row[c];
      softmax_tail(x, e, S);
      float s = e[cls + 1] / S;
      if (s >= TH && (sel < 0 || bin05(s) >= sel)) {
        int pos = atomicAdd(&s_n, 1);
        if (pos < CAP) {
          unsigned int key = __float_as_uint(s) | 0x80000000u;
          cand[pos] = ((unsigned long long)(key ^ 0xFFFFFFFFu) << 32) |
                      (unsigned long long)(unsigned int)n;
        }
      }
    }
  }
  __syncthreads();
  int ncand = s_n; if (ncand > CAP) ncand = CAP;

  // hybrid bitonic sort (register element; shfl j<=32, LDS j>=64)
  unsigned long long v = (tid < ncand) ? cand[tid] : ~0ULL;
  for (int k = 2; k <= CAP; k <<= 1) {
    const bool up = ((tid & k) == 0);
    for (int j = k >> 1; j >= 64; j >>= 1) {
      cand[tid] = v;
      __syncthreads();
      unsigned long long o = cand[tid ^ j];
      bool keepMin = (((tid & j) == 0) == up);
      v = ((v < o) == keepMin) ? v : o;
      __syncthreads();
    }
    for (int j = (k >> 1) < 32 ? (k >> 1) : 32; j >= 1; j >>= 1) {
      unsigned long long o = shflx64(v, j);
      bool keepMin = (((tid & j) == 0) == up);
      v = ((v < o) == keepMin) ? v : o;
    }
  }
  const int nsel = (ncand < TOPK) ? ncand : TOPK;

  // decode (exact reference op order) -> SoA
  if (tid < TOPK) {
    float x1 = 0.f, y1 = 0.f, x2 = 0.f, y2 = 0.f, s = 0.f, ar = 0.f;
    if (tid < nsel) {
      unsigned int key = (unsigned int)(v >> 32) ^ 0xFFFFFFFFu;
      s = __uint_as_float(key ^ 0x80000000u);
      int idx = (int)(unsigned int)(v & 0xFFFFFFFFu);
      float4 anc = ((const float4*)anchors)[idx];
      float4 l   = ((const float4*)loc)[(long long)b * NANCH + idx];
      float cx = anc.x + (l.x * 0.1f) * anc.z;
      float cy = anc.y + (l.y * 0.1f) * anc.w;
      float w  = anc.z * expf(l.z * 0.2f);
      float h  = anc.w * expf(l.w * 0.2f);
      x1 = cx - 0.5f * w; y1 = cy - 0.5f * h;
      x2 = cx + 0.5f * w; y2 = cy + 0.5f * h;
      ar = fmaxf(x2 - x1, 0.0f) * fmaxf(y2 - y1, 0.0f);
    }
    int o = bc * TOPK + tid;
    soa[0 * SOA_N + o] = x1;
    soa[1 * SOA_N + o] = y1;
    soa[2 * SOA_N + o] = x2;
    soa[3 * SOA_N + o] = y2;
    soa[4 * SOA_N + o] = s;
    soa[5 * SOA_N + o] = ar;
  }
  if (tid == 0) nselg[bc * CNTSTRIDE] = nsel;
}

// ---------------- K3: balanced pairwise IoU -> adjacency bitmasks ----------
__global__ __launch_bounds__(256) void iou_kernel(
    const float* __restrict__ soa, unsigned long long* __restrict__ adjg) {
  const int bc = blockIdx.x;
  const int tid = threadIdx.x;
  __shared__ float x1s[TOPK], y1s[TOPK], x2s[TOPK], y2s[TOPK], ars[TOPK];
  __shared__ unsigned long long adj[TOPK][4];

  if (tid < TOPK) {
    int o = bc * TOPK + tid;
    x1s[tid] = soa[0 * SOA_N + o];
    y1s[tid] = soa[1 * SOA_N + o];
    x2s[tid] = soa[2 * SOA_N + o];
    y2s[tid] = soa[3 * SOA_N + o];
    ars[tid] = soa[5 * SOA_N + o];
  }
  for (int i = tid; i < TOPK * 4; i += 256) ((unsigned long long*)adj)[i] = 0;
  __syncthreads();

  for (int p = tid; p < NPAIRS; p += 256) {
    float xr = (399.0f - sqrtf((float)(159201 - 8 * p))) * 0.5f;
    int i = (int)xr;
    if (i > 198) i = 198;
    while (i * (399 - i) / 2 > p) --i;
    while ((i + 1) * (398 - i) / 2 <= p) ++i;
    int j = i + 1 + (p - i * (399 - i) / 2);
    float ltx = fmaxf(x1s[i], x1s[j]);
    float lty = fmaxf(y1s[i], y1s[j]);
    float rbx = fminf(x2s[i], x2s[j]);
    float rby = fminf(y2s[i], y2s[j]);
    float iw = fmaxf(rbx - ltx, 0.0f);
    float ih = fmaxf(rby - lty, 0.0f);
    float inter = iw * ih;
    float uni = ars[i] + ars[j] - inter;
    float um = fmaxf(uni, 1e-9f);
    float half = 0.5f * um;
    bool hit;
    if (inter > half * 1.000001f)      hit = true;
    else if (inter < half * 0.999999f) hit = false;
    else                               hit = (inter / um > 0.5f);  // rare
    if (hit) atomicOr(&adj[i][j >> 6], 1ULL << (j & 63));
  }
  __syncthreads();
  for (int i = tid; i < TOPK * 4; i += 256)
    adjg[(long long)bc * (TOPK * 4) + i] = ((unsigned long long*)adj)[i];
}

// ---------------- K4: register greedy NMS (readlane broadcast) + output -----
__global__ __launch_bounds__(64) void greedy_out_kernel(
    const unsigned long long* __restrict__ adjg, const int* __restrict__ nselg,
    const float* __restrict__ soa, float* __restrict__ out) {
  const int bc = blockIdx.x;
  const int l  = threadIdx.x;            // one wave
  const int nsel = nselg[bc * CNTSTRIDE];
  const unsigned long long* A = adjg + (long long)bc * (TOPK * 4);

  // lane l holds rows l, l+64, l+128, l+192(<8)
  unsigned long long r0[4], r1[4], r2[4], r3[4];
#pragma unroll
  for (int w = 0; w < 4; ++w) {
    r0[w] = A[(l) * 4 + w];
    r1[w] = A[(l + 64) * 4 + w];
    r2[w] = (l < 72) ? A[(l + 128) * 4 + w] : 0ULL;   // rows 128..199
    r3[w] = (l < 8)  ? A[(l + 192) * 4 + w] : 0ULL;   // rows 192..199
  }
  unsigned long long sup0 = 0, sup1 = 0, sup2 = 0, sup3 = 0;
  unsigned long long k0 = 0, k1 = 0, k2 = 0, k3 = 0;
  for (int ii = 0; ii < TOPK; ++ii) {
    const int w = ii >> 6, bit = ii & 63;
    unsigned long long supw = (w == 0) ? sup0 : (w == 1) ? sup1
                            : (w == 2) ? sup2 : sup3;
    bool kept = (ii < nsel) && !((supw >> bit) & 1ULL);   // uniform
    if (kept) {
      unsigned long long a0, a1, a2, a3;
      if (w == 0)      { a0=rl64(r0[0],bit); a1=rl64(r0[1],bit);
                         a2=rl64(r0[2],bit); a3=rl64(r0[3],bit); k0 |= 1ULL<<bit; }
      else if (w == 1) { a0=rl64(r1[0],bit); a1=rl64(r1[1],bit);
                         a2=rl64(r1[2],bit); a3=rl64(r1[3],bit); k1 |= 1ULL<<bit; }
      else if (w == 2) { a0=rl64(r2[0],bit); a1=rl64(r2[1],bit);
                         a2=rl64(r2[2],bit); a3=rl64(r2[3],bit); k2 |= 1ULL<<bit; }
      else             { a0=rl64(r3[0],bit); a1=rl64(r3[1],bit);
                         a2=rl64(r3[2],bit); a3=rl64(r3[3],bit); k3 |= 1ULL<<bit; }
      sup0 |= a0; sup1 |= a1; sup2 |= a2; sup3 |= a3;
    }
  }
  // output: (B, 20, 200, 5)
  for (int r = l; r < TOPK; r += 64) {
    unsigned long long kw = (r < 64) ? k0 : (r < 128) ? k1 : (r < 192) ? k2 : k3;
    bool k = (kw >> (r & 63)) & 1ULL;
    int o = bc * TOPK + r;
    float* po = out + (long long)o * 5;
    po[0] = k ? soa[0 * SOA_N + o] : 0.0f;
    po[1] = k ? soa[1 * SOA_N + o] : 0.0f;
    po[2] = k ? soa[2 * SOA_N + o] : 0.0f;
    po[3] = k ? soa[3 * SOA_N + o] : 0.0f;
    po[4] = k ? soa[4 * SOA_N + o] : 0.0f;
  }
}

extern "C" void kernel_launch(void* const* d_in, const int* in_sizes, int n_in,
                              void* d_out, int out_size, void* d_ws, size_t ws_size,
                              hipStream_t stream) {
  const float* conf    = (const float*)d_in[0];
  const float* loc     = (const float*)d_in[1];
  const float* anchors = (const float*)d_in[2];
  float* out = (float*)d_out;

  char* ws = (char*)d_ws;
  unsigned long long* cand  = (unsigned long long*)(ws + OFF_CAND);
  unsigned int*       cnt   = (unsigned int*)(ws + OFF_CNT);
  float*              soa   = (float*)(ws + OFF_SOA);
  int*                nselg = (int*)(ws + OFF_NSEL);
  unsigned long long* adjg  = (unsigned long long*)(ws + OFF_ADJ);

  hipMemsetAsync(ws + OFF_CNT, 0, 320 * CNTSTRIDE * 4, stream);
  softmax_collect_kernel<<<(NB * NANCH) / 256, 256, 0, stream>>>(conf, cnt, cand);
  select_sort_decode_kernel<<<NCOL, 256, 0, stream>>>(cand, cnt, conf, loc,
                                                      anchors, soa, nselg);
  iou_kernel<<<NCOL, 256, 0, stream>>>(soa, adjg);
  greedy_out_kernel<<<NCOL, 64, 0, stream>>>(adjg, nselg, soa, out);
}